// Round 7
// baseline (230.746 us; speedup 1.0000x reference)
//
#include <hip/hip_runtime.h>
#include <hip/hip_bf16.h>

// ---------------------------------------------------------------------------
// OrthoInitPhasor round 7 — single fused main kernel
//   prep_all:     pack Wv/Wo, cvt Wkm/Wqm, transpose Wk/Wq, compose biases
//   gemm_compose: Wkk = Wkm@Wk, Wqq = Wqm@Wq via MFMA
//   fused_all:    per 64-token chunk: x-tile->LDS, 3 MFMA passes (Q,K,V) with
//                 B streamed from L2-resident Wall, in-register phasor +
//                 cumsum (shuffle scan), LN, MFMA GEMM vs Wo, +bo+x -> out
// ---------------------------------------------------------------------------

typedef __attribute__((ext_vector_type(8))) short short8;   // 8 x bf16
typedef __attribute__((ext_vector_type(4))) float f32x4;

#define M_TOK   16384
#define DIM     512
#define APAD    520   // LDS row stride (bf16 elems): 1040 B, 16B-aligned

__device__ __forceinline__ void gll16(const void* g, void* l) {
  __builtin_amdgcn_global_load_lds(
      (const __attribute__((address_space(1))) unsigned int*)g,
      (__attribute__((address_space(3))) unsigned int*)l, 16, 0, 0);
}

__device__ __forceinline__ uint2 pack4bf(float4 v) {
  union { __hip_bfloat16 h[4]; uint2 u; } t;
  t.h[0] = __float2bfloat16(v.x);
  t.h[1] = __float2bfloat16(v.y);
  t.h[2] = __float2bfloat16(v.z);
  t.h[3] = __float2bfloat16(v.w);
  return t.u;
}

__device__ __forceinline__ unsigned packbf2(float a, float b) {
  union { __hip_bfloat16 h[2]; unsigned u; } t;
  t.h[0] = __float2bfloat16(a);
  t.h[1] = __float2bfloat16(b);
  return t.u;
}

__device__ __forceinline__ float bflo(unsigned u) {
  union { unsigned x; float f; } t; t.x = u << 16; return t.f;
}
__device__ __forceinline__ float bfhi(unsigned u) {
  union { unsigned x; float f; } t; t.x = u & 0xffff0000u; return t.f;
}

// ------------------------------ prep (weights) -----------------------------
// blocks 0..511    : pack Wv -> Wall[0:512), Wo -> Wall[1536:2048); bv -> bc1
// blocks 512..1023 : cvt Wkm/Wqm -> Wm_bf
// blocks 1024..1151: transpose-cvt Wk/Wq -> WT_bf (64x64 tiles)
// blocks 1152..1407: compose biases (wave per row)
__global__ __launch_bounds__(256) void prep_all(
    const float* __restrict__ Wv, const float* __restrict__ Wo,
    const float* __restrict__ bv,
    const float* __restrict__ Wkm, const float* __restrict__ Wqm,
    const float* __restrict__ Wk, const float* __restrict__ Wq,
    const float* __restrict__ bk, const float* __restrict__ bkm,
    const float* __restrict__ bq, const float* __restrict__ bqm,
    __hip_bfloat16* __restrict__ Wall, float* __restrict__ bc1,
    __hip_bfloat16* __restrict__ Wm_bf, __hip_bfloat16* __restrict__ WT_bf) {
  const int tid = threadIdx.x;
  const int b = blockIdx.x;
  if (b < 512) {
    int m = b >> 8;
    int idx = ((b & 255) * 256 + tid) * 4;
    const float* src = m ? Wo : Wv;
    __hip_bfloat16* dst = Wall + (m ? (size_t)1536 * 512 : 0);
    ((uint2*)dst)[idx >> 2] = pack4bf(*(const float4*)(src + idx));
    int t = b * 256 + tid;
    if (t < 512) bc1[t] = bv[t];
  } else if (b < 1024) {
    int bb = b - 512;
    int m = bb >> 8;
    int idx = ((bb & 255) * 256 + tid) * 4;
    const float* src = m ? Wqm : Wkm;
    ((uint2*)(Wm_bf + (size_t)m * 262144))[idx >> 2] =
        pack4bf(*(const float4*)(src + idx));
  } else if (b < 1152) {
    __shared__ float tile[64][65];
    int bb = b - 1024;
    int z = bb >> 6;
    int tl = bb & 63;
    int tr = tl >> 3, tc = tl & 7;
#pragma unroll
    for (int i = 0; i < 4; i++) {
      int r = (tid >> 4) + 16 * i;
      int c4 = (tid & 15) * 4;
      float4 v = *(const float4*)((z ? Wq : Wk) +
                                  (size_t)(tr * 64 + r) * 512 + tc * 64 + c4);
      tile[r][c4 + 0] = v.x;
      tile[r][c4 + 1] = v.y;
      tile[r][c4 + 2] = v.z;
      tile[r][c4 + 3] = v.w;
    }
    __syncthreads();
    int orow = tid >> 2;
    int seg = tid & 3;
    __hip_bfloat16* dst = WT_bf + (size_t)z * 262144 +
                          (size_t)(tc * 64 + orow) * 512 + tr * 64 + seg * 16;
#pragma unroll
    for (int qq = 0; qq < 4; qq++) {
      float4 v;
      v.x = tile[seg * 16 + qq * 4 + 0][orow];
      v.y = tile[seg * 16 + qq * 4 + 1][orow];
      v.z = tile[seg * 16 + qq * 4 + 2][orow];
      v.w = tile[seg * 16 + qq * 4 + 3][orow];
      *(uint2*)(dst + qq * 4) = pack4bf(v);
    }
  } else {
    int row = (b - 1152) * 4 + (tid >> 6);
    int lane = tid & 63;
    int z = row >> 9;
    int i = row & 511;
    const float* Wm = z ? Wqm : Wkm;
    const float* b0 = z ? bq : bk;
    const float* bm = z ? bqm : bkm;
    const float4* w4 = (const float4*)(Wm + (size_t)i * 512 + lane * 8);
    const float4* v4 = (const float4*)(b0 + lane * 8);
    float4 w0 = w4[0], w1 = w4[1], c0 = v4[0], c1 = v4[1];
    float acc = w0.x * c0.x + w0.y * c0.y + w0.z * c0.z + w0.w * c0.w +
                w1.x * c1.x + w1.y * c1.y + w1.z * c1.z + w1.w * c1.w;
#pragma unroll
    for (int off = 32; off; off >>= 1) acc += __shfl_xor(acc, off, 64);
    if (lane == 0) bc1[512 + z * 512 + i] = acc + bm[i];
  }
}

// --------------- compose GEMM: Wkk=Wkm@Wk, Wqq=Wqm@Wq (MFMA) ---------------
__global__ __launch_bounds__(256) void gemm_compose(
    const __hip_bfloat16* __restrict__ Wm_bf,
    const __hip_bfloat16* __restrict__ WT_bf,
    __hip_bfloat16* __restrict__ Wall) {
  constexpr int K = 512, BK = 32;
  const __hip_bfloat16* A  = Wm_bf + (size_t)blockIdx.z * 262144;
  const __hip_bfloat16* Bt = WT_bf + (size_t)blockIdx.z * 262144;
  __hip_bfloat16* C = Wall + (size_t)(512 + blockIdx.z * 512) * 512;
  __shared__ __align__(16) __hip_bfloat16 As[128 * BK];
  __shared__ __align__(16) __hip_bfloat16 Bs[128 * BK];

  const int tid  = threadIdx.x;
  const int lane = tid & 63;
  const int w    = tid >> 6;
  const int wm   = w >> 1;
  const int wn   = w & 1;
  const int m0   = blockIdx.y * 128;
  const int n0   = blockIdx.x * 128;

  const int rS0    = (w * 2 + 0) * 16 + (lane >> 2);
  const int rS1    = (w * 2 + 1) * 16 + (lane >> 2);
  const int kInRow = (lane & 3) * 8;
  const __hip_bfloat16* gA0 = A + (size_t)(m0 + rS0) * K + kInRow;
  const __hip_bfloat16* gA1 = A + (size_t)(m0 + rS1) * K + kInRow;
  const __hip_bfloat16* gB0 = Bt + (size_t)(n0 + rS0) * K + kInRow;
  const __hip_bfloat16* gB1 = Bt + (size_t)(n0 + rS1) * K + kInRow;
  char* ldsA0 = (char*)As + (w * 2 + 0) * 1024;
  char* ldsA1 = (char*)As + (w * 2 + 1) * 1024;
  char* ldsB0 = (char*)Bs + (w * 2 + 0) * 1024;
  char* ldsB1 = (char*)Bs + (w * 2 + 1) * 1024;

  f32x4 acc[4][4] = {};
  const int rfA = lane & 15;
  const int rfK = (lane >> 4) * 8;

  for (int kt = 0; kt < K; kt += BK) {
    __syncthreads();
    gll16(gA0 + kt, ldsA0);
    gll16(gA1 + kt, ldsA1);
    gll16(gB0 + kt, ldsB0);
    gll16(gB1 + kt, ldsB1);
    __syncthreads();

    short8 af[4], bf[4];
#pragma unroll
    for (int i = 0; i < 4; i++)
      af[i] = *(const short8*)(As + (wm * 64 + i * 16 + rfA) * BK + rfK);
#pragma unroll
    for (int j = 0; j < 4; j++)
      bf[j] = *(const short8*)(Bs + (wn * 64 + j * 16 + rfA) * BK + rfK);
#pragma unroll
    for (int i = 0; i < 4; i++)
#pragma unroll
      for (int j = 0; j < 4; j++)
        acc[i][j] = __builtin_amdgcn_mfma_f32_16x16x32_bf16(
            af[i], bf[j], acc[i][j], 0, 0, 0);
  }

  const int cq = lane >> 4;
#pragma unroll
  for (int i = 0; i < 4; i++) {
    int row = m0 + wm * 64 + i * 16 + cq * 4;
#pragma unroll
    for (int j = 0; j < 4; j++) {
      int col = n0 + wn * 64 + j * 16 + (lane & 15);
#pragma unroll
      for (int r = 0; r < 4; r++)
        C[(size_t)(row + r) * 512 + col] = __float2bfloat16(acc[i][j][r]);
    }
  }
}

// --------------------------- fused main kernel -----------------------------
// grid 256 (= B*nC), 1024 threads (16 waves). Wave wv owns d-range
// [wv*32, wv*32+32). Lane (q=lane>>4, c=lane&15) owns rows i*16+q*4+r and
// cols d0+16j (d0 = wv*32+c, j=0,1) — IDENTICAL across all passes, so the
// phasor consumes MFMA accumulators directly from registers.
__device__ __forceinline__ void mfma_pass(
    const __hip_bfloat16* __restrict__ Alds,   // stride APAD, LDS
    const __hip_bfloat16* __restrict__ Bt,     // [512,512] row-major, global
    int c, int q, int d0, f32x4 acc[4][2]) {
  const int rfK = q * 8;
  for (int kt = 0; kt < 512; kt += 32) {
    short8 af[4], bf[2];
#pragma unroll
    for (int j = 0; j < 2; j++)
      bf[j] = *(const short8*)(Bt + (size_t)(d0 + 16 * j) * 512 + kt + rfK);
#pragma unroll
    for (int i = 0; i < 4; i++)
      af[i] = *(const short8*)(Alds + (i * 16 + c) * APAD + kt + rfK);
#pragma unroll
    for (int i = 0; i < 4; i++)
#pragma unroll
      for (int j = 0; j < 2; j++)
        acc[i][j] = __builtin_amdgcn_mfma_f32_16x16x32_bf16(
            af[i], bf[j], acc[i][j], 0, 0, 0);
  }
}

__global__ __launch_bounds__(1024) void fused_all(
    const float* __restrict__ x,               // [16384,512] f32
    const __hip_bfloat16* __restrict__ Wall,   // [2048,512]: Wv|Wkk|Wqq|Wo
    const float* __restrict__ bc1,             // [1536]: bv|bkk|bqq
    const float* __restrict__ bp,              // [4096,512]
    const float* __restrict__ mod_scale,
    const float* __restrict__ ln_g, const float* __restrict__ ln_b,
    const float* __restrict__ bo,
    float* __restrict__ out) {
  __shared__ __hip_bfloat16 At[64 * APAD];     // x-tile bf16 (66.5 KB)
  __shared__ __hip_bfloat16 R[64 * APAD];      // qp plane -> retrieved/normed
  const int tid    = threadIdx.x;
  const int lane   = tid & 63;
  const int wv     = tid >> 6;                 // 0..15
  const int q      = lane >> 4;
  const int c      = lane & 15;
  const int token0 = blockIdx.x * 64;
  const int sg0    = (blockIdx.x & 63) * 64;
  const float msc  = mod_scale[0];
  const float isd  = 0.044194173824159216f;    // 1/sqrt(512)
  const int d0     = wv * 32 + c;

  // ---- stage x-tile (f32 -> bf16) into At ----
  {
    const float4* xs = (const float4*)(x + (size_t)token0 * 512);
#pragma unroll
    for (int kc = 0; kc < 8; kc++) {
      int idx = kc * 1024 + tid;               // float4 index (8192 total)
      int row = idx >> 7;
      int col4 = idx & 127;
      *(uint2*)((char*)At + row * (APAD * 2) + col4 * 8) = pack4bf(xs[idx]);
    }
  }
  __syncthreads();

  // ---- pass Q: qp -> R plane (bf16, own-lane slots, no barrier needed) ----
  {
    f32x4 acc[4][2] = {};
    mfma_pass(At, Wall + (size_t)1024 * 512, c, q, d0, acc);
    float bq0 = bc1[1024 + d0], bq1 = bc1[1024 + d0 + 16];
#pragma unroll
    for (int i = 0; i < 4; i++)
#pragma unroll
      for (int r = 0; r < 4; r++) {
        int s = i * 16 + q * 4 + r;
        const float* bprow = bp + (size_t)(sg0 + s) * 512;
        R[s * APAD + d0] =
            __float2bfloat16(bprow[d0] + (acc[i][0][r] + bq0) * msc);
        R[s * APAD + d0 + 16] =
            __float2bfloat16(bprow[d0 + 16] + (acc[i][1][r] + bq1) * msc);
      }
  }

  // ---- pass K: kp -> (ck,sk) packed bf16x2 in registers ----
  unsigned cksk[4][2][4];
  {
    f32x4 acc[4][2] = {};
    mfma_pass(At, Wall + (size_t)512 * 512, c, q, d0, acc);
    float bk0 = bc1[512 + d0], bk1 = bc1[512 + d0 + 16];
#pragma unroll
    for (int i = 0; i < 4; i++)
#pragma unroll
      for (int r = 0; r < 4; r++) {
        int s = i * 16 + q * 4 + r;
        const float* bprow = bp + (size_t)(sg0 + s) * 512;
        float kp0 = bprow[d0] + (acc[i][0][r] + bk0) * msc;
        float kp1 = bprow[d0 + 16] + (acc[i][1][r] + bk1) * msc;
        float s0, c0, s1, c1;
        __sincosf(kp0, &s0, &c0);
        __sincosf(kp1, &s1, &c1);
        cksk[i][0][r] = packbf2(c0, s0);
        cksk[i][1][r] = packbf2(c1, s1);
      }
  }

  // ---- pass V + in-register cumsum + retrieved -> R ----
  {
    f32x4 acc[4][2] = {};
    mfma_pass(At, Wall, c, q, d0, acc);
    float bv0 = bc1[d0], bv1 = bc1[d0 + 16];
#pragma unroll
    for (int j = 0; j < 2; j++) {
      const int d = d0 + 16 * j;
      const float bvj = j ? bv1 : bv0;
      float carry_r = 0.f, carry_i = 0.f;
#pragma unroll
      for (int i = 0; i < 4; i++) {
        float br[4], bi[4];
#pragma unroll
        for (int r = 0; r < 4; r++) {
          float v = acc[i][j][r] + bvj;
          unsigned pk = cksk[i][j][r];
          br[r] = v * bflo(pk);
          bi[r] = v * bfhi(pk);
        }
        br[1] += br[0]; br[2] += br[1]; br[3] += br[2];
        bi[1] += bi[0]; bi[2] += bi[1]; bi[3] += bi[2];
        float Sr = br[3], Si = bi[3];
        float s0r = __shfl(Sr, c, 64),      s0i = __shfl(Si, c, 64);
        float s1r = __shfl(Sr, 16 + c, 64), s1i = __shfl(Si, 16 + c, 64);
        float s2r = __shfl(Sr, 32 + c, 64), s2i = __shfl(Si, 32 + c, 64);
        float s3r = __shfl(Sr, 48 + c, 64), s3i = __shfl(Si, 48 + c, 64);
        float Er = (q > 0 ? s0r : 0.f) + (q > 1 ? s1r : 0.f) +
                   (q > 2 ? s2r : 0.f);
        float Ei = (q > 0 ? s0i : 0.f) + (q > 1 ? s1i : 0.f) +
                   (q > 2 ? s2i : 0.f);
#pragma unroll
        for (int r = 0; r < 4; r++) {
          float mr = br[r] + Er + carry_r;
          float mi = bi[r] + Ei + carry_i;
          int s = i * 16 + q * 4 + r;
          float qp = __bfloat162float(R[s * APAD + d]);
          float sq, cq2;
          __sincosf(qp, &sq, &cq2);
          R[s * APAD + d] = __float2bfloat16((mr * cq2 + mi * sq) * isd);
        }
        carry_r += s0r + s1r + s2r + s3r;
        carry_i += s0i + s1i + s2i + s3i;
      }
    }
  }
  __syncthreads();

  // ---- LayerNorm in place (wave wv owns rows wv*4..+3) ----
  {
    float gj[8], bj[8];
#pragma unroll
    for (int j = 0; j < 8; j++) {
      int col = lane + 64 * j;
      gj[j] = ln_g[col];
      bj[j] = ln_b[col];
    }
    for (int rr = 0; rr < 4; ++rr) {
      int row = wv * 4 + rr;
      float vals[8], sum = 0.f, sq2 = 0.f;
#pragma unroll
      for (int j = 0; j < 8; j++) {
        float v = __bfloat162float(R[row * APAD + lane + 64 * j]);
        vals[j] = v;
        sum += v;
        sq2 += v * v;
      }
#pragma unroll
      for (int off = 32; off; off >>= 1) {
        sum += __shfl_xor(sum, off, 64);
        sq2 += __shfl_xor(sq2, off, 64);
      }
      float mu   = sum * (1.f / 512.f);
      float var  = sq2 * (1.f / 512.f) - mu * mu;
      float rstd = rsqrtf(var + 1e-5f);
#pragma unroll
      for (int j = 0; j < 8; j++) {
        float nv = (vals[j] - mu) * rstd * gj[j] + bj[j];
        R[row * APAD + lane + 64 * j] = __float2bfloat16(nv);
      }
    }
  }
  __syncthreads();

  // ---- GEMM_O: out = R @ Wo^T + bo + x ----
  {
    f32x4 acc[4][2] = {};
    mfma_pass(R, Wall + (size_t)1536 * 512, c, q, d0, acc);
    float bz0 = bo[d0], bz1 = bo[d0 + 16];
#pragma unroll
    for (int i = 0; i < 4; i++)
#pragma unroll
      for (int j = 0; j < 2; j++) {
        int col = d0 + 16 * j;
        float bz = j ? bz1 : bz0;
#pragma unroll
        for (int r = 0; r < 4; r++) {
          int row = token0 + i * 16 + q * 4 + r;
          size_t o = (size_t)row * 512 + col;
          out[o] = acc[i][j][r] + bz + x[o];
        }
      }
  }
}

// ------------------------------- launcher ----------------------------------
extern "C" void kernel_launch(void* const* d_in, const int* in_sizes, int n_in,
                              void* d_out, int out_size, void* d_ws,
                              size_t ws_size, hipStream_t stream) {
  const float* x    = (const float*)d_in[0];
  const float* bp   = (const float*)d_in[1];
  const float* Wk   = (const float*)d_in[2];
  const float* bk   = (const float*)d_in[3];
  const float* Wv   = (const float*)d_in[4];
  const float* bv   = (const float*)d_in[5];
  const float* Wq   = (const float*)d_in[6];
  const float* bq   = (const float*)d_in[7];
  const float* Wkm  = (const float*)d_in[8];
  const float* bkm  = (const float*)d_in[9];
  const float* Wqm  = (const float*)d_in[10];
  const float* bqm  = (const float*)d_in[11];
  const float* msc  = (const float*)d_in[12];
  const float* lng  = (const float*)d_in[13];
  const float* lnb  = (const float*)d_in[14];
  const float* Wo   = (const float*)d_in[15];
  const float* bo   = (const float*)d_in[16];
  float* out = (float*)d_out;

  char* ws = (char*)d_ws;
  __hip_bfloat16* Wall  = (__hip_bfloat16*)ws;  ws += (size_t)2048 * 512 * 2;
  __hip_bfloat16* Wm_bf = (__hip_bfloat16*)ws;  ws += (size_t)2 * 262144 * 2;
  __hip_bfloat16* WT_bf = (__hip_bfloat16*)ws;  ws += (size_t)2 * 262144 * 2;
  float*          bc1   = (float*)ws;           ws += 1536 * 4;

  // 1) prep: pack/cvt/transpose weights + compose biases
  prep_all<<<1408, 256, 0, stream>>>(Wv, Wo, bv, Wkm, Wqm, Wk, Wq, bk, bkm,
                                     bq, bqm, Wall, bc1, Wm_bf, WT_bf);
  // 2) MFMA compose: Wkk, Wqq -> Wall rows 512..1535
  gemm_compose<<<dim3(4, 4, 2), 256, 0, stream>>>(Wm_bf, WT_bf, Wall);
  // 3) everything else, fused: one block per 64-token chunk
  fused_all<<<256, 1024, 0, stream>>>(x, Wall, bc1, bp, msc, lng, lnb, bo,
                                      out);
}

// Round 9
// 212.316 us; speedup vs baseline: 1.0868x; 1.0868x over previous
//
#include <hip/hip_runtime.h>
#include <hip/hip_bf16.h>

// ---------------------------------------------------------------------------
// OrthoInitPhasor round 9 (R8 + staging-width fix)
//   prep_all:     cvt x->bf16, pack Wv/Wo, cvt Wkm/Wqm, transpose Wk/Wq,
//                 compose biases
//   gemm_compose: Wkk = Wkm@Wk, Wqq = Wqm@Wq via MFMA
//   GEMM_A:       x @ [Wv|Wkk|Wqq]^T + bias -> VKQ planar [16384,1536] bf16
//   fused_pg2:    windowed-LDS-staged phasor + 4-seg split-scan cumsum + LN
//                 + MFMA GEMM vs Wo + resid -> out
// ---------------------------------------------------------------------------

typedef __attribute__((ext_vector_type(8))) short short8;   // 8 x bf16
typedef __attribute__((ext_vector_type(4))) float f32x4;

#define M_TOK   16384
#define DIM     512
#define RPAD    520   // LDS row stride (bf16 elems)

__device__ __forceinline__ void gll16(const void* g, void* l) {
  __builtin_amdgcn_global_load_lds(
      (const __attribute__((address_space(1))) unsigned int*)g,
      (__attribute__((address_space(3))) unsigned int*)l, 16, 0, 0);
}

__device__ __forceinline__ uint2 pack4bf(float4 v) {
  union { __hip_bfloat16 h[4]; uint2 u; } t;
  t.h[0] = __float2bfloat16(v.x);
  t.h[1] = __float2bfloat16(v.y);
  t.h[2] = __float2bfloat16(v.z);
  t.h[3] = __float2bfloat16(v.w);
  return t.u;
}

__device__ __forceinline__ unsigned packbf2(float a, float b) {
  union { __hip_bfloat16 h[2]; unsigned u; } t;
  t.h[0] = __float2bfloat16(a);
  t.h[1] = __float2bfloat16(b);
  return t.u;
}

__device__ __forceinline__ float bflo(unsigned u) {
  union { unsigned x; float f; } t; t.x = u << 16; return t.f;
}
__device__ __forceinline__ float bfhi(unsigned u) {
  union { unsigned x; float f; } t; t.x = u & 0xffff0000u; return t.f;
}

// ------------------------------ prep (merged) ------------------------------
__global__ __launch_bounds__(256) void prep_all(
    const float* __restrict__ x, __hip_bfloat16* __restrict__ x_bf,
    const float* __restrict__ Wv, const float* __restrict__ Wo,
    const float* __restrict__ bv,
    const float* __restrict__ Wkm, const float* __restrict__ Wqm,
    const float* __restrict__ Wk, const float* __restrict__ Wq,
    const float* __restrict__ bk, const float* __restrict__ bkm,
    const float* __restrict__ bq, const float* __restrict__ bqm,
    __hip_bfloat16* __restrict__ Wall, float* __restrict__ bc1,
    __hip_bfloat16* __restrict__ Wm_bf, __hip_bfloat16* __restrict__ WT_bf) {
  const int tid = threadIdx.x;
  if (blockIdx.x < 8192) {
    int i = blockIdx.x * 256 + tid;
    ((uint2*)x_bf)[i] = pack4bf(((const float4*)x)[i]);
    return;
  }
  const int b = blockIdx.x - 8192;
  if (b < 512) {
    int m = b >> 8;
    int idx = ((b & 255) * 256 + tid) * 4;
    const float* src = m ? Wo : Wv;
    __hip_bfloat16* dst = Wall + (m ? (size_t)1536 * 512 : 0);
    ((uint2*)dst)[idx >> 2] = pack4bf(*(const float4*)(src + idx));
    int t = b * 256 + tid;
    if (t < 512) bc1[t] = bv[t];
  } else if (b < 1024) {
    int bb = b - 512;
    int m = bb >> 8;
    int idx = ((bb & 255) * 256 + tid) * 4;
    const float* src = m ? Wqm : Wkm;
    ((uint2*)(Wm_bf + (size_t)m * 262144))[idx >> 2] =
        pack4bf(*(const float4*)(src + idx));
  } else if (b < 1152) {
    __shared__ float tile[64][65];
    int bb = b - 1024;
    int z = bb >> 6;
    int tl = bb & 63;
    int tr = tl >> 3, tc = tl & 7;
#pragma unroll
    for (int i = 0; i < 4; i++) {
      int r = (tid >> 4) + 16 * i;
      int c4 = (tid & 15) * 4;
      float4 v = *(const float4*)((z ? Wq : Wk) +
                                  (size_t)(tr * 64 + r) * 512 + tc * 64 + c4);
      tile[r][c4 + 0] = v.x;
      tile[r][c4 + 1] = v.y;
      tile[r][c4 + 2] = v.z;
      tile[r][c4 + 3] = v.w;
    }
    __syncthreads();
    int orow = tid >> 2;
    int seg = tid & 3;
    __hip_bfloat16* dst = WT_bf + (size_t)z * 262144 +
                          (size_t)(tc * 64 + orow) * 512 + tr * 64 + seg * 16;
#pragma unroll
    for (int qq = 0; qq < 4; qq++) {
      float4 v;
      v.x = tile[seg * 16 + qq * 4 + 0][orow];
      v.y = tile[seg * 16 + qq * 4 + 1][orow];
      v.z = tile[seg * 16 + qq * 4 + 2][orow];
      v.w = tile[seg * 16 + qq * 4 + 3][orow];
      *(uint2*)(dst + qq * 4) = pack4bf(v);
    }
  } else {
    int row = (b - 1152) * 4 + (tid >> 6);
    int lane = tid & 63;
    int z = row >> 9;
    int i = row & 511;
    const float* Wm = z ? Wqm : Wkm;
    const float* b0 = z ? bq : bk;
    const float* bm = z ? bqm : bkm;
    const float4* w4 = (const float4*)(Wm + (size_t)i * 512 + lane * 8);
    const float4* v4 = (const float4*)(b0 + lane * 8);
    float4 w0 = w4[0], w1 = w4[1], c0 = v4[0], c1 = v4[1];
    float acc = w0.x * c0.x + w0.y * c0.y + w0.z * c0.z + w0.w * c0.w +
                w1.x * c1.x + w1.y * c1.y + w1.z * c1.z + w1.w * c1.w;
#pragma unroll
    for (int off = 32; off; off >>= 1) acc += __shfl_xor(acc, off, 64);
    if (lane == 0) bc1[512 + z * 512 + i] = acc + bm[i];
  }
}

// ------------------------------- GEMM (B^T) --------------------------------
__global__ __launch_bounds__(256) void gemm_bt(
    const __hip_bfloat16* __restrict__ A, int lda,
    const __hip_bfloat16* __restrict__ Bt,
    const float* __restrict__ bias,
    __hip_bfloat16* __restrict__ Cout, int ldc) {
  constexpr int K = 512, BK = 32;
  __shared__ __align__(16) __hip_bfloat16 As[128 * BK];
  __shared__ __align__(16) __hip_bfloat16 Bs[128 * BK];

  const int tid  = threadIdx.x;
  const int lane = tid & 63;
  const int w    = tid >> 6;
  const int wm   = w >> 1;
  const int wn   = w & 1;
  const int m0   = blockIdx.y * 128;
  const int n0   = blockIdx.x * 128;

  const int rS0    = (w * 2 + 0) * 16 + (lane >> 2);
  const int rS1    = (w * 2 + 1) * 16 + (lane >> 2);
  const int kInRow = (lane & 3) * 8;
  const __hip_bfloat16* gA0 = A + (size_t)(m0 + rS0) * lda + kInRow;
  const __hip_bfloat16* gA1 = A + (size_t)(m0 + rS1) * lda + kInRow;
  const __hip_bfloat16* gB0 = Bt + (size_t)(n0 + rS0) * K + kInRow;
  const __hip_bfloat16* gB1 = Bt + (size_t)(n0 + rS1) * K + kInRow;
  char* ldsA0 = (char*)As + (w * 2 + 0) * 1024;
  char* ldsA1 = (char*)As + (w * 2 + 1) * 1024;
  char* ldsB0 = (char*)Bs + (w * 2 + 0) * 1024;
  char* ldsB1 = (char*)Bs + (w * 2 + 1) * 1024;

  f32x4 acc[4][4] = {};

  const int rfA = lane & 15;
  const int rfK = (lane >> 4) * 8;

  for (int kt = 0; kt < K; kt += BK) {
    __syncthreads();
    gll16(gA0 + kt, ldsA0);
    gll16(gA1 + kt, ldsA1);
    gll16(gB0 + kt, ldsB0);
    gll16(gB1 + kt, ldsB1);
    __syncthreads();

    short8 af[4], bf[4];
#pragma unroll
    for (int i = 0; i < 4; i++)
      af[i] = *(const short8*)(As + (wm * 64 + i * 16 + rfA) * BK + rfK);
#pragma unroll
    for (int j = 0; j < 4; j++)
      bf[j] = *(const short8*)(Bs + (wn * 64 + j * 16 + rfA) * BK + rfK);
#pragma unroll
    for (int i = 0; i < 4; i++)
#pragma unroll
      for (int j = 0; j < 4; j++)
        acc[i][j] = __builtin_amdgcn_mfma_f32_16x16x32_bf16(
            af[i], bf[j], acc[i][j], 0, 0, 0);
  }

  const int cq = lane >> 4;
#pragma unroll
  for (int i = 0; i < 4; i++) {
    int row = m0 + wm * 64 + i * 16 + cq * 4;
#pragma unroll
    for (int j = 0; j < 4; j++) {
      int col = n0 + wn * 64 + j * 16 + (lane & 15);
      float bz = bias[col];
#pragma unroll
      for (int r = 0; r < 4; r++) {
        float v = acc[i][j][r] + bz;
        Cout[(size_t)(row + r) * ldc + col] = __float2bfloat16(v);
      }
    }
  }
}

// --------------- compose GEMM: Wkk=Wkm@Wk, Wqq=Wqm@Wq (MFMA) ---------------
__global__ __launch_bounds__(256) void gemm_compose(
    const __hip_bfloat16* __restrict__ Wm_bf,
    const __hip_bfloat16* __restrict__ WT_bf,
    __hip_bfloat16* __restrict__ Wall) {
  constexpr int K = 512, BK = 32;
  const __hip_bfloat16* A  = Wm_bf + (size_t)blockIdx.z * 262144;
  const __hip_bfloat16* Bt = WT_bf + (size_t)blockIdx.z * 262144;
  __hip_bfloat16* C = Wall + (size_t)(512 + blockIdx.z * 512) * 512;
  __shared__ __align__(16) __hip_bfloat16 As[128 * BK];
  __shared__ __align__(16) __hip_bfloat16 Bs[128 * BK];

  const int tid  = threadIdx.x;
  const int lane = tid & 63;
  const int w    = tid >> 6;
  const int wm   = w >> 1;
  const int wn   = w & 1;
  const int m0   = blockIdx.y * 128;
  const int n0   = blockIdx.x * 128;

  const int rS0    = (w * 2 + 0) * 16 + (lane >> 2);
  const int rS1    = (w * 2 + 1) * 16 + (lane >> 2);
  const int kInRow = (lane & 3) * 8;
  const __hip_bfloat16* gA0 = A + (size_t)(m0 + rS0) * K + kInRow;
  const __hip_bfloat16* gA1 = A + (size_t)(m0 + rS1) * K + kInRow;
  const __hip_bfloat16* gB0 = Bt + (size_t)(n0 + rS0) * K + kInRow;
  const __hip_bfloat16* gB1 = Bt + (size_t)(n0 + rS1) * K + kInRow;
  char* ldsA0 = (char*)As + (w * 2 + 0) * 1024;
  char* ldsA1 = (char*)As + (w * 2 + 1) * 1024;
  char* ldsB0 = (char*)Bs + (w * 2 + 0) * 1024;
  char* ldsB1 = (char*)Bs + (w * 2 + 1) * 1024;

  f32x4 acc[4][4] = {};
  const int rfA = lane & 15;
  const int rfK = (lane >> 4) * 8;

  for (int kt = 0; kt < K; kt += BK) {
    __syncthreads();
    gll16(gA0 + kt, ldsA0);
    gll16(gA1 + kt, ldsA1);
    gll16(gB0 + kt, ldsB0);
    gll16(gB1 + kt, ldsB1);
    __syncthreads();

    short8 af[4], bf[4];
#pragma unroll
    for (int i = 0; i < 4; i++)
      af[i] = *(const short8*)(As + (wm * 64 + i * 16 + rfA) * BK + rfK);
#pragma unroll
    for (int j = 0; j < 4; j++)
      bf[j] = *(const short8*)(Bs + (wn * 64 + j * 16 + rfA) * BK + rfK);
#pragma unroll
    for (int i = 0; i < 4; i++)
#pragma unroll
      for (int j = 0; j < 4; j++)
        acc[i][j] = __builtin_amdgcn_mfma_f32_16x16x32_bf16(
            af[i], bf[j], acc[i][j], 0, 0, 0);
  }

  const int cq = lane >> 4;
#pragma unroll
  for (int i = 0; i < 4; i++) {
    int row = m0 + wm * 64 + i * 16 + cq * 4;
#pragma unroll
    for (int j = 0; j < 4; j++) {
      int col = n0 + wn * 64 + j * 16 + (lane & 15);
#pragma unroll
      for (int r = 0; r < 4; r++)
        C[(size_t)(row + r) * 512 + col] = __float2bfloat16(acc[i][j][r]);
    }
  }
}

// ---- fused: staged phasor + 4-seg split-scan + LN + GEMM(Wo) + resid ------
// grid 256 (= B*nC), 1024 threads (16 waves). One chunk (64 tokens) / block.
// Scan: seg = tid>>8 handles s in [seg*16, seg*16+16); thread owns columns
// d0 = (tid&255)*2 and d0+1. Windows of 4 s-rows per seg are staged into 4
// LDS planes {V, Km, Qm, bp} coalesced (uint4 = 8 bf16 per lane), then
// consumed with one b32 per plane (2 columns at once).
__global__ __launch_bounds__(1024) void fused_pg2(
    const __hip_bfloat16* __restrict__ VKQ,   // [16384,1536] planar
    const float* __restrict__ bp,             // [4096,512]
    const float* __restrict__ mod_scale,
    const float* __restrict__ ln_g, const float* __restrict__ ln_b,
    const __hip_bfloat16* __restrict__ WoB,   // [512,512] bf16
    const float* __restrict__ bo,
    const float* __restrict__ x,              // resid f32
    float* __restrict__ out) {
  __shared__ __align__(16) __hip_bfloat16 SP[4][16][RPAD];  // 66.5 KB
  __shared__ __align__(16) __hip_bfloat16 R[64 * RPAD];     // 66.5 KB
  __shared__ float Tpre[3][2][512];                         // 12 KB
  const int tid    = threadIdx.x;
  const int token0 = blockIdx.x * 64;
  const int sg0    = (blockIdx.x & 63) * 64;
  const float msc  = mod_scale[0];
  const float isd  = 0.044194173824159216f;   // 1/sqrt(512)

  const int seg = tid >> 8;                   // scan segment 0..3
  const int d0  = (tid & 255) * 2;            // even column

  const int ssl  = tid >> 6;                  // staging slot 0..15
  const int sm   = tid & 63;                  // staging within-row
  const int sseg = ssl >> 2;
  const int sj   = ssl & 3;

  float mr0 = 0.f, mi0 = 0.f, mr1 = 0.f, mi1 = 0.f;
  unsigned qt0[16], qt1[16];

#pragma unroll
  for (int w = 0; w < 4; ++w) {
    __syncthreads();
    // ---- stage 16 rows (4 per seg) of V/Km/Qm/bp, coalesced 16B ----
    {
      int srow = sseg * 16 + w * 4 + sj;
      const __hip_bfloat16* g =
          VKQ + (size_t)(token0 + srow) * 1536 + sm * 8;
      *(uint4*)&SP[0][ssl][sm * 8] = *(const uint4*)(g);
      *(uint4*)&SP[1][ssl][sm * 8] = *(const uint4*)(g + 512);
      *(uint4*)&SP[2][ssl][sm * 8] = *(const uint4*)(g + 1024);
      const float* gb = bp + (size_t)(sg0 + srow) * 512 + sm * 8;
      float4 b0 = *(const float4*)gb;
      float4 b1 = *(const float4*)(gb + 4);
      uint4 pb;
      pb.x = packbf2(b0.x, b0.y);
      pb.y = packbf2(b0.z, b0.w);
      pb.z = packbf2(b1.x, b1.y);
      pb.w = packbf2(b1.z, b1.w);
      *(uint4*)&SP[3][ssl][sm * 8] = pb;
    }
    __syncthreads();
    // ---- 4 scan steps from LDS (1 b32 per plane = 2 columns) ----
#pragma unroll
    for (int j = 0; j < 4; ++j) {
      int sl = seg * 4 + j;
      unsigned uv = *(const unsigned*)&SP[0][sl][d0];
      unsigned uk = *(const unsigned*)&SP[1][sl][d0];
      unsigned uq = *(const unsigned*)&SP[2][sl][d0];
      unsigned ub = *(const unsigned*)&SP[3][sl][d0];
      float v0 = bflo(uv), v1 = bfhi(uv);
      float k0 = bflo(uk), k1 = bfhi(uk);
      float q0 = bflo(uq), q1 = bfhi(uq);
      float b0 = bflo(ub), b1 = bfhi(ub);
      float kp0 = b0 + k0 * msc, qp0 = b0 + q0 * msc;
      float kp1 = b1 + k1 * msc, qp1 = b1 + q1 * msc;
      float sk0, ck0, sq0, cq0, sk1, ck1, sq1, cq1;
      __sincosf(kp0, &sk0, &ck0);
      __sincosf(qp0, &sq0, &cq0);
      __sincosf(kp1, &sk1, &ck1);
      __sincosf(qp1, &sq1, &cq1);
      mr0 += v0 * ck0; mi0 += v0 * sk0;
      mr1 += v1 * ck1; mi1 += v1 * sk1;
      float r0 = (mr0 * cq0 + mi0 * sq0) * isd;
      float r1 = (mr1 * cq1 + mi1 * sq1) * isd;
      int s = seg * 16 + w * 4 + j;
      *(unsigned*)&R[s * RPAD + d0] = packbf2(r0, r1);
      int si = w * 4 + j;
      if (seg > 0) {
        qt0[si] = packbf2(cq0, sq0);
        qt1[si] = packbf2(cq1, sq1);
      }
    }
  }
  // ---- publish per-seg totals (scaled by isd) ----
  if (seg < 3) {
    Tpre[seg][0][d0]     = mr0 * isd;
    Tpre[seg][0][d0 + 1] = mr1 * isd;
    Tpre[seg][1][d0]     = mi0 * isd;
    Tpre[seg][1][d0 + 1] = mi1 * isd;
  }
  __syncthreads();
  // ---- fixup: add scan prefix to segs 1..3 ----
  if (seg > 0) {
    float Pr0 = 0.f, Pi0 = 0.f, Pr1 = 0.f, Pi1 = 0.f;
    for (int k = 0; k < seg; ++k) {
      Pr0 += Tpre[k][0][d0];
      Pr1 += Tpre[k][0][d0 + 1];
      Pi0 += Tpre[k][1][d0];
      Pi1 += Tpre[k][1][d0 + 1];
    }
#pragma unroll
    for (int si = 0; si < 16; ++si) {
      int s = seg * 16 + si;
      unsigned ur = *(const unsigned*)&R[s * RPAD + d0];
      float r0 = bflo(ur) + Pr0 * bflo(qt0[si]) + Pi0 * bfhi(qt0[si]);
      float r1 = bfhi(ur) + Pr1 * bflo(qt1[si]) + Pi1 * bfhi(qt1[si]);
      *(unsigned*)&R[s * RPAD + d0] = packbf2(r0, r1);
    }
  }
  __syncthreads();

  // ---- LayerNorm in place (wave wv owns rows wv*4..+3) ----
  {
    const int lane = tid & 63;
    const int wv   = tid >> 6;
    float gj[8], bj[8];
#pragma unroll
    for (int j = 0; j < 8; j++) {
      int col = lane + 64 * j;
      gj[j] = ln_g[col];
      bj[j] = ln_b[col];
    }
    for (int rr = 0; rr < 4; ++rr) {
      int row = wv * 4 + rr;
      float vals[8], sum = 0.f, sq2 = 0.f;
#pragma unroll
      for (int j = 0; j < 8; j++) {
        float v = __bfloat162float(R[row * RPAD + lane + 64 * j]);
        vals[j] = v;
        sum += v;
        sq2 += v * v;
      }
#pragma unroll
      for (int off = 32; off; off >>= 1) {
        sum += __shfl_xor(sum, off, 64);
        sq2 += __shfl_xor(sq2, off, 64);
      }
      float mu   = sum * (1.f / 512.f);
      float var  = sq2 * (1.f / 512.f) - mu * mu;
      float rstd = rsqrtf(var + 1e-5f);
#pragma unroll
      for (int j = 0; j < 8; j++) {
        float nv = (vals[j] - mu) * rstd * gj[j] + bj[j];
        R[row * RPAD + lane + 64 * j] = __float2bfloat16(nv);
      }
    }
  }
  __syncthreads();

  // ---- phase 2: C(64x512) = R @ Wo^T + bo + x -> out (16 waves) ----
  {
    const int lane = tid & 63;
    const int wv   = tid >> 6;                // wave -> cols wv*32..+31
    const int rfA  = lane & 15;
    const int rfK  = (lane >> 4) * 8;
    const int dw0  = wv * 32;
    f32x4 acc[4][2] = {};

    for (int kt = 0; kt < 512; kt += 32) {
      short8 af[4], bf[2];
#pragma unroll
      for (int j = 0; j < 2; j++) {
        int col = dw0 + j * 16 + rfA;
        bf[j] = *(const short8*)(WoB + (size_t)col * 512 + kt + rfK);
      }
#pragma unroll
      for (int i = 0; i < 4; i++)
        af[i] = *(const short8*)(R + (i * 16 + rfA) * RPAD + kt + rfK);
#pragma unroll
      for (int i = 0; i < 4; i++)
#pragma unroll
        for (int j = 0; j < 2; j++)
          acc[i][j] = __builtin_amdgcn_mfma_f32_16x16x32_bf16(
              af[i], bf[j], acc[i][j], 0, 0, 0);
    }

    const int cq = lane >> 4;
    float bz[2];
#pragma unroll
    for (int j = 0; j < 2; j++) bz[j] = bo[dw0 + j * 16 + (lane & 15)];
#pragma unroll
    for (int i = 0; i < 4; i++) {
      int row = token0 + i * 16 + cq * 4;
#pragma unroll
      for (int j = 0; j < 2; j++) {
        int col = dw0 + j * 16 + (lane & 15);
#pragma unroll
        for (int r = 0; r < 4; r++) {
          size_t o = (size_t)(row + r) * 512 + col;
          out[o] = acc[i][j][r] + bz[j] + x[o];
        }
      }
    }
  }
}

// ------------------------------- launcher ----------------------------------
extern "C" void kernel_launch(void* const* d_in, const int* in_sizes, int n_in,
                              void* d_out, int out_size, void* d_ws,
                              size_t ws_size, hipStream_t stream) {
  const float* x    = (const float*)d_in[0];
  const float* bp   = (const float*)d_in[1];
  const float* Wk   = (const float*)d_in[2];
  const float* bk   = (const float*)d_in[3];
  const float* Wv   = (const float*)d_in[4];
  const float* bv   = (const float*)d_in[5];
  const float* Wq   = (const float*)d_in[6];
  const float* bq   = (const float*)d_in[7];
  const float* Wkm  = (const float*)d_in[8];
  const float* bkm  = (const float*)d_in[9];
  const float* Wqm  = (const float*)d_in[10];
  const float* bqm  = (const float*)d_in[11];
  const float* msc  = (const float*)d_in[12];
  const float* lng  = (const float*)d_in[13];
  const float* lnb  = (const float*)d_in[14];
  const float* Wo   = (const float*)d_in[15];
  const float* bo   = (const float*)d_in[16];
  float* out = (float*)d_out;

  char* ws = (char*)d_ws;
  __hip_bfloat16* x_bf  = (__hip_bfloat16*)ws;  ws += (size_t)M_TOK * DIM * 2;
  __hip_bfloat16* Wall  = (__hip_bfloat16*)ws;  ws += (size_t)2048 * 512 * 2;
  __hip_bfloat16* Wm_bf = (__hip_bfloat16*)ws;  ws += (size_t)2 * 262144 * 2;
  __hip_bfloat16* WT_bf = (__hip_bfloat16*)ws;  ws += (size_t)2 * 262144 * 2;
  float*          bc1   = (float*)ws;           ws += 1536 * 4;
  __hip_bfloat16* VKQ   = (__hip_bfloat16*)ws;  ws += (size_t)M_TOK * 1536 * 2;

  // 1) merged prep: cvt x + pack/cvt/transpose weights + compose biases
  prep_all<<<9600, 256, 0, stream>>>(x, x_bf, Wv, Wo, bv, Wkm, Wqm, Wk, Wq,
                                     bk, bkm, bq, bqm, Wall, bc1, Wm_bf,
                                     WT_bf);
  // 2) MFMA compose: Wkk, Wqq -> Wall rows 512..1535
  gemm_compose<<<dim3(4, 4, 2), 256, 0, stream>>>(Wm_bf, WT_bf, Wall);
  // 3) VKQ = x @ [Wv|Wkk|Wqq]^T + bias, planar [16384,1536]
  gemm_bt<<<dim3(12, 128), 256, 0, stream>>>(x_bf, DIM, Wall, bc1, VKQ, 1536);
  // 4) fused staged phasor + split-scan + LN + GEMM(Wo) + bo + resid -> out
  fused_pg2<<<256, 1024, 0, stream>>>(VKQ, bp, msc, lng, lnb,
                                      Wall + (size_t)1536 * 512, bo, x, out);
}